// Round 1
// baseline (1964.773 us; speedup 1.0000x reference)
//
#include <hip/hip_runtime.h>
#include <math.h>

#define N_NODES 50000
#define N_EDGES 1600000
#define D_IN 128
#define D_H 64
#define N_CLS 10
#define N_GRAPHS 64
#define NEG_SLOPE 0.2f
#define E2 (N_EDGES + N_NODES)   // edges + self loops

// ---- float <-> orderable-uint encoding for atomicMax on floats ----
__device__ inline unsigned f2o(float f) {
    unsigned u = __float_as_uint(f);
    return (u & 0x80000000u) ? ~u : (u | 0x80000000u);
}
__device__ inline float o2f(unsigned u) {
    return (u & 0x80000000u) ? __uint_as_float(u & 0x7fffffffu)
                             : __uint_as_float(~u);
}

__device__ inline float wave_reduce_sum(float v) {
    for (int off = 32; off; off >>= 1) v += __shfl_xor(v, off);
    return v;
}

// ---- mean of edge_attr (sum; divided by E at use site) ----
__global__ void sum_eattr(const float* __restrict__ ea, float* esum, int E) {
    int i = blockIdx.x * blockDim.x + threadIdx.x;
    float v = 0.f;
    for (; i < E; i += gridDim.x * blockDim.x) v += ea[i];
    v = wave_reduce_sum(v);
    if ((threadIdx.x & 63) == 0) atomicAdd(esum, v);
}

// ---- xl = x@Wl + bl ; xr = x@Wr + br.  One wave per node, lane = out dim ----
__global__ void linear_dual(const float* __restrict__ x, int K,
                            const float* __restrict__ Wl, const float* __restrict__ bl,
                            const float* __restrict__ Wr, const float* __restrict__ br,
                            float* __restrict__ xl, float* __restrict__ xr, int n) {
    int node = blockIdx.x * (blockDim.x >> 6) + (threadIdx.x >> 6);
    int d = threadIdx.x & 63;
    if (node >= n) return;
    const float* xrow = x + (size_t)node * K;
    float al = bl[d], ar = br[d];
    for (int k = 0; k < K; ++k) {
        float xv = xrow[k];
        al = fmaf(xv, Wl[k * D_H + d], al);
        ar = fmaf(xv, Wr[k * D_H + d], ar);
    }
    xl[(size_t)node * D_H + d] = al;
    xr[(size_t)node * D_H + d] = ar;
}

// ---- pass A: per-edge attention logit + segment max.  One wave per edge ----
__global__ void edge_logits(const int* __restrict__ src, const int* __restrict__ dst,
                            const float* __restrict__ eattr,
                            const float* __restrict__ xl, const float* __restrict__ xr,
                            const float* __restrict__ We, const float* __restrict__ att,
                            const float* __restrict__ esum,
                            float* __restrict__ zbuf, unsigned* __restrict__ m_enc) {
    int wid = blockIdx.x * (blockDim.x >> 6) + (threadIdx.x >> 6);
    int d = threadIdx.x & 63;
    if (wid >= E2) return;
    int s, t; float ea;
    if (wid < N_EDGES) { s = src[wid]; t = dst[wid]; ea = eattr[wid]; }
    else { s = t = wid - N_EDGES; ea = esum[0] * (1.0f / N_EDGES); }
    float v = xl[(size_t)s * D_H + d] + xr[(size_t)t * D_H + d] + ea * We[d];
    v = v > 0.f ? v : NEG_SLOPE * v;
    float p = wave_reduce_sum(v * att[d]);
    if (d == 0) {
        zbuf[wid] = p;
        atomicMax(m_enc + t, f2o(p));
    }
}

// ---- pass B: z = exp(logit - m[dst]); accumulate denominator ----
__global__ void edge_exp(const int* __restrict__ dst, const unsigned* __restrict__ m_enc,
                         float* __restrict__ zbuf, float* __restrict__ ssum) {
    int e = blockIdx.x * blockDim.x + threadIdx.x;
    if (e >= E2) return;
    int t = (e < N_EDGES) ? dst[e] : (e - N_EDGES);
    float z = expf(zbuf[e] - o2f(m_enc[t]));
    zbuf[e] = z;
    atomicAdd(ssum + t, z);
}

// ---- pass C: out[dst] += alpha * xl[src].  One wave per edge ----
__global__ void edge_aggr(const int* __restrict__ src, const int* __restrict__ dst,
                          const float* __restrict__ xl,
                          const float* __restrict__ zbuf, const float* __restrict__ ssum,
                          float* __restrict__ acc) {
    int wid = blockIdx.x * (blockDim.x >> 6) + (threadIdx.x >> 6);
    int d = threadIdx.x & 63;
    if (wid >= E2) return;
    int s, t;
    if (wid < N_EDGES) { s = src[wid]; t = dst[wid]; }
    else { s = t = wid - N_EDGES; }
    float alpha = zbuf[wid] / (ssum[t] + 1e-16f);
    atomicAdd(acc + (size_t)t * D_H + d, alpha * xl[(size_t)s * D_H + d]);
}

// ---- + bias, ELU (in place) ----
__global__ void finish_elu(float* __restrict__ acc, const float* __restrict__ b) {
    int i = blockIdx.x * blockDim.x + threadIdx.x;
    if (i >= N_NODES * D_H) return;
    float h = acc[i] + b[i & (D_H - 1)];
    acc[i] = h > 0.f ? h : expm1f(h);
}

// ---- global mean pool (batch is sorted): register accumulate, flush on change ----
__global__ void pool(const float* __restrict__ h, const int* __restrict__ batch,
                     float* __restrict__ pooled, float* __restrict__ counts) {
    const int CHUNK = 128;
    int base = blockIdx.x * CHUNK;
    int d = threadIdx.x;  // blockDim = 64
    float accv = 0.f; int cur_g = -1; int cnt = 0;
    for (int i = 0; i < CHUNK; ++i) {
        int n = base + i;
        if (n >= N_NODES) break;
        int g = batch[n];
        if (g != cur_g) {
            if (cur_g >= 0) {
                atomicAdd(&pooled[cur_g * D_H + d], accv);
                if (d == 0) atomicAdd(&counts[cur_g], (float)cnt);
            }
            cur_g = g; accv = 0.f; cnt = 0;
        }
        accv += h[(size_t)n * D_H + d];
        cnt++;
    }
    if (cur_g >= 0) {
        atomicAdd(&pooled[cur_g * D_H + d], accv);
        if (d == 0) atomicAdd(&counts[cur_g], (float)cnt);
    }
}

// ---- classifier: out[g,c] = bc[c] + sum_k (pooled[g,k]/count[g]) * Wc[k,c] ----
__global__ void classify(const float* __restrict__ pooled, const float* __restrict__ counts,
                         const float* __restrict__ Wc, const float* __restrict__ bc,
                         float* __restrict__ out) {
    int tid = threadIdx.x;             // 640 threads
    int g = tid / N_CLS, c = tid % N_CLS;
    if (g >= N_GRAPHS) return;
    float inv = 1.0f / fmaxf(counts[g], 1.0f);
    float a = bc[c];
    for (int k = 0; k < D_H; ++k)
        a = fmaf(pooled[g * D_H + k] * inv, Wc[k * N_CLS + c], a);
    out[g * N_CLS + c] = a;
}

extern "C" void kernel_launch(void* const* d_in, const int* in_sizes, int n_in,
                              void* d_out, int out_size, void* d_ws, size_t ws_size,
                              hipStream_t stream) {
    const float* x     = (const float*)d_in[0];
    const int*   ei    = (const int*)d_in[1];
    const float* eattr = (const float*)d_in[2];
    const int*   batch = (const int*)d_in[3];
    const float *Wl1 = (const float*)d_in[4],  *bl1 = (const float*)d_in[5];
    const float *Wr1 = (const float*)d_in[6],  *br1 = (const float*)d_in[7];
    const float *We1 = (const float*)d_in[8],  *att1 = (const float*)d_in[9];
    const float *b1  = (const float*)d_in[10];
    const float *Wl2 = (const float*)d_in[11], *bl2 = (const float*)d_in[12];
    const float *Wr2 = (const float*)d_in[13], *br2 = (const float*)d_in[14];
    const float *We2 = (const float*)d_in[15], *att2 = (const float*)d_in[16];
    const float *b2  = (const float*)d_in[17];
    const float *Wc  = (const float*)d_in[18], *bc = (const float*)d_in[19];
    float* out = (float*)d_out;

    const int* src = ei;
    const int* dst = ei + N_EDGES;

    // workspace layout
    float* ws = (float*)d_ws;
    float* xl     = ws;                                 // N*64
    float* xr     = xl + (size_t)N_NODES * D_H;         // N*64
    float* acc1   = xr + (size_t)N_NODES * D_H;         // N*64
    float* acc2   = acc1 + (size_t)N_NODES * D_H;       // N*64
    float* zbuf   = acc2 + (size_t)N_NODES * D_H;       // E2
    unsigned* m_enc = (unsigned*)(zbuf + E2);           // N
    float* ssum   = (float*)(m_enc + N_NODES);          // N
    float* pooled = ssum + N_NODES;                     // 64*64
    float* counts = pooled + N_GRAPHS * D_H;            // 64
    float* esum   = counts + N_GRAPHS;                  // 1

    const int WPB = 4;  // waves per block at 256 threads
    int edge_wave_blocks = (E2 + WPB - 1) / WPB;
    int node_wave_blocks = (N_NODES + WPB - 1) / WPB;

    hipMemsetAsync(esum, 0, sizeof(float), stream);
    sum_eattr<<<256, 256, 0, stream>>>(eattr, esum, N_EDGES);

    // ---------------- layer 1 ----------------
    linear_dual<<<node_wave_blocks, 256, 0, stream>>>(x, D_IN, Wl1, bl1, Wr1, br1, xl, xr, N_NODES);
    hipMemsetAsync(m_enc, 0, N_NODES * sizeof(unsigned), stream);
    hipMemsetAsync(ssum, 0, N_NODES * sizeof(float), stream);
    hipMemsetAsync(acc1, 0, (size_t)N_NODES * D_H * sizeof(float), stream);
    edge_logits<<<edge_wave_blocks, 256, 0, stream>>>(src, dst, eattr, xl, xr, We1, att1, esum, zbuf, m_enc);
    edge_exp<<<(E2 + 255) / 256, 256, 0, stream>>>(dst, m_enc, zbuf, ssum);
    edge_aggr<<<edge_wave_blocks, 256, 0, stream>>>(src, dst, xl, zbuf, ssum, acc1);
    finish_elu<<<(N_NODES * D_H + 255) / 256, 256, 0, stream>>>(acc1, b1);

    // ---------------- layer 2 ----------------
    linear_dual<<<node_wave_blocks, 256, 0, stream>>>(acc1, D_H, Wl2, bl2, Wr2, br2, xl, xr, N_NODES);
    hipMemsetAsync(m_enc, 0, N_NODES * sizeof(unsigned), stream);
    hipMemsetAsync(ssum, 0, N_NODES * sizeof(float), stream);
    hipMemsetAsync(acc2, 0, (size_t)N_NODES * D_H * sizeof(float), stream);
    edge_logits<<<edge_wave_blocks, 256, 0, stream>>>(src, dst, eattr, xl, xr, We2, att2, esum, zbuf, m_enc);
    edge_exp<<<(E2 + 255) / 256, 256, 0, stream>>>(dst, m_enc, zbuf, ssum);
    edge_aggr<<<edge_wave_blocks, 256, 0, stream>>>(src, dst, xl, zbuf, ssum, acc2);
    finish_elu<<<(N_NODES * D_H + 255) / 256, 256, 0, stream>>>(acc2, b2);

    // ---------------- pool + classify ----------------
    hipMemsetAsync(pooled, 0, (N_GRAPHS * D_H + N_GRAPHS) * sizeof(float), stream);
    pool<<<(N_NODES + 127) / 128, 64, 0, stream>>>(acc2, batch, pooled, counts);
    classify<<<1, 640, 0, stream>>>(pooled, counts, Wc, bc, out);
}

// Round 2
// 1627.871 us; speedup vs baseline: 1.2070x; 1.2070x over previous
//
#include <hip/hip_runtime.h>
#include <math.h>

#define N_NODES 50000
#define N_EDGES 1600000
#define D_IN 128
#define D_H 64
#define N_CLS 10
#define N_GRAPHS 64
#define NEG_SLOPE 0.2f
#define E2 (N_EDGES + N_NODES)   // edges + self loops

__device__ inline float wave_reduce_sum(float v) {
    for (int off = 32; off; off >>= 1) v += __shfl_xor(v, off);
    return v;
}
__device__ inline float wave_reduce_max(float v) {
    for (int off = 32; off; off >>= 1) v = fmaxf(v, __shfl_xor(v, off));
    return v;
}

// ---- mean of edge_attr (sum; divided by E at use site) ----
__global__ void sum_eattr(const float* __restrict__ ea, float* esum, int E) {
    int i = blockIdx.x * blockDim.x + threadIdx.x;
    float v = 0.f;
    for (; i < E; i += gridDim.x * blockDim.x) v += ea[i];
    v = wave_reduce_sum(v);
    if ((threadIdx.x & 63) == 0) atomicAdd(esum, v);
}

// ============== CSR build (graph is shared by both layers) ==============
__global__ void init_counts(int* cnt) {
    int i = blockIdx.x * blockDim.x + threadIdx.x;
    if (i < N_NODES) cnt[i] = 1;   // self loop
}
__global__ void hist_dst(const int* __restrict__ dst, int* cnt) {
    int e = blockIdx.x * blockDim.x + threadIdx.x;
    if (e < N_EDGES) atomicAdd(&cnt[dst[e]], 1);
}
// exclusive scan of cnt[0..N) -> row_start[0..N], single block of 1024
__global__ void exscan(const int* __restrict__ cnt, int* __restrict__ row_start) {
    __shared__ int sdata[1024];
    __shared__ int soff;
    if (threadIdx.x == 0) soff = 0;
    __syncthreads();
    for (int base = 0; base < N_NODES; base += 1024) {
        int i = base + threadIdx.x;
        int v = (i < N_NODES) ? cnt[i] : 0;
        sdata[threadIdx.x] = v;
        __syncthreads();
        for (int off = 1; off < 1024; off <<= 1) {
            int t = (threadIdx.x >= off) ? sdata[threadIdx.x - off] : 0;
            __syncthreads();
            sdata[threadIdx.x] += t;
            __syncthreads();
        }
        int incl = sdata[threadIdx.x];
        if (i < N_NODES) row_start[i] = soff + incl - v;
        __syncthreads();
        if (threadIdx.x == 1023) soff += incl;
        __syncthreads();
    }
    if (threadIdx.x == 0) row_start[N_NODES] = soff;
}
__global__ void scatter_edges(const int* __restrict__ src, const int* __restrict__ dst,
                              int* cursor, int* __restrict__ csr_src, int* __restrict__ posbuf) {
    int e = blockIdx.x * blockDim.x + threadIdx.x;
    if (e >= N_EDGES) return;
    int t = dst[e];
    int p = atomicAdd(&cursor[t], 1);
    csr_src[p] = src[e];
    posbuf[e] = p;
}
__global__ void scatter_self(int* cursor, int* __restrict__ csr_src, int* __restrict__ posbuf) {
    int n = blockIdx.x * blockDim.x + threadIdx.x;
    if (n >= N_NODES) return;
    int p = atomicAdd(&cursor[n], 1);
    csr_src[p] = n;
    posbuf[N_EDGES + n] = p;
}

// ---- xl = x@Wl + bl ; xr = x@Wr + br.  One wave per node, lane = out dim ----
__global__ void linear_dual(const float* __restrict__ x, int K,
                            const float* __restrict__ Wl, const float* __restrict__ bl,
                            const float* __restrict__ Wr, const float* __restrict__ br,
                            float* __restrict__ xl, float* __restrict__ xr, int n) {
    int node = blockIdx.x * (blockDim.x >> 6) + (threadIdx.x >> 6);
    int d = threadIdx.x & 63;
    if (node >= n) return;
    const float* xrow = x + (size_t)node * K;
    float al = bl[d], ar = br[d];
    for (int k = 0; k < K; ++k) {
        float xv = xrow[k];
        al = fmaf(xv, Wl[k * D_H + d], al);
        ar = fmaf(xv, Wr[k * D_H + d], ar);
    }
    xl[(size_t)node * D_H + d] = al;
    xr[(size_t)node * D_H + d] = ar;
}

// ---- per-edge attention logit, written into its CSR slot ----
__global__ void edge_logits(const int* __restrict__ src, const int* __restrict__ dst,
                            const float* __restrict__ eattr,
                            const float* __restrict__ xl, const float* __restrict__ xr,
                            const float* __restrict__ We, const float* __restrict__ att,
                            const float* __restrict__ esum, const int* __restrict__ posbuf,
                            float* __restrict__ zsort) {
    int wid = blockIdx.x * (blockDim.x >> 6) + (threadIdx.x >> 6);
    int d = threadIdx.x & 63;
    if (wid >= E2) return;
    int s, t; float ea;
    if (wid < N_EDGES) { s = src[wid]; t = dst[wid]; ea = eattr[wid]; }
    else { s = t = wid - N_EDGES; ea = esum[0] * (1.0f / N_EDGES); }
    float v = xl[(size_t)s * D_H + d] + xr[(size_t)t * D_H + d] + ea * We[d];
    v = v > 0.f ? v : NEG_SLOPE * v;
    float p = wave_reduce_sum(v * att[d]);
    if (d == 0) zsort[posbuf[wid]] = p;
}

// ---- per-node softmax over the contiguous CSR row (in place -> alpha) ----
__global__ void node_softmax(const int* __restrict__ row_start, float* __restrict__ zsort) {
    int node = blockIdx.x * (blockDim.x >> 6) + (threadIdx.x >> 6);
    int lane = threadIdx.x & 63;
    if (node >= N_NODES) return;
    int j0 = row_start[node], j1 = row_start[node + 1];
    int deg = j1 - j0;
    if (deg <= 64) {                       // common case: one element per lane
        int j = j0 + lane;
        float z = (j < j1) ? zsort[j] : -INFINITY;
        float m = wave_reduce_max(z);
        float e = (j < j1) ? expf(z - m) : 0.f;
        float s = wave_reduce_sum(e);
        if (j < j1) zsort[j] = e / (s + 1e-16f);
    } else {
        float m = -INFINITY;
        for (int j = j0 + lane; j < j1; j += 64) m = fmaxf(m, zsort[j]);
        m = wave_reduce_max(m);
        float s = 0.f;
        for (int j = j0 + lane; j < j1; j += 64) s += expf(zsort[j] - m);
        s = wave_reduce_sum(s);
        float inv = 1.f / (s + 1e-16f);
        for (int j = j0 + lane; j < j1; j += 64) zsort[j] = expf(zsort[j] - m) * inv;
    }
}

// ---- per-node aggregation: out = ELU( sum_j alpha_j * xl[src_j] + b ) ----
__global__ void node_aggr(const int* __restrict__ row_start, const int* __restrict__ csr_src,
                          const float* __restrict__ zsort, const float* __restrict__ xl,
                          const float* __restrict__ b, float* __restrict__ out) {
    int node = blockIdx.x * (blockDim.x >> 6) + (threadIdx.x >> 6);
    int d = threadIdx.x & 63;
    if (node >= N_NODES) return;
    int j0 = row_start[node], j1 = row_start[node + 1];
    float acc = 0.f;
    int j = j0;
    for (; j + 1 < j1; j += 2) {    // 2-wide to expose memory-level parallelism
        int s0 = csr_src[j], s1 = csr_src[j + 1];
        float a0 = zsort[j], a1 = zsort[j + 1];
        float v0 = xl[(size_t)s0 * D_H + d];
        float v1 = xl[(size_t)s1 * D_H + d];
        acc = fmaf(a0, v0, acc);
        acc = fmaf(a1, v1, acc);
    }
    if (j < j1) {
        int s0 = csr_src[j];
        acc = fmaf(zsort[j], xl[(size_t)s0 * D_H + d], acc);
    }
    float h = acc + b[d];
    out[(size_t)node * D_H + d] = h > 0.f ? h : expm1f(h);
}

// ---- global mean pool (batch is sorted): register accumulate, flush on change ----
__global__ void pool(const float* __restrict__ h, const int* __restrict__ batch,
                     float* __restrict__ pooled, float* __restrict__ counts) {
    const int CHUNK = 128;
    int base = blockIdx.x * CHUNK;
    int d = threadIdx.x;  // blockDim = 64
    float accv = 0.f; int cur_g = -1; int cnt = 0;
    for (int i = 0; i < CHUNK; ++i) {
        int n = base + i;
        if (n >= N_NODES) break;
        int g = batch[n];
        if (g != cur_g) {
            if (cur_g >= 0) {
                atomicAdd(&pooled[cur_g * D_H + d], accv);
                if (d == 0) atomicAdd(&counts[cur_g], (float)cnt);
            }
            cur_g = g; accv = 0.f; cnt = 0;
        }
        accv += h[(size_t)n * D_H + d];
        cnt++;
    }
    if (cur_g >= 0) {
        atomicAdd(&pooled[cur_g * D_H + d], accv);
        if (d == 0) atomicAdd(&counts[cur_g], (float)cnt);
    }
}

__global__ void classify(const float* __restrict__ pooled, const float* __restrict__ counts,
                         const float* __restrict__ Wc, const float* __restrict__ bc,
                         float* __restrict__ out) {
    int tid = threadIdx.x;             // 640 threads
    int g = tid / N_CLS, c = tid % N_CLS;
    if (g >= N_GRAPHS) return;
    float inv = 1.0f / fmaxf(counts[g], 1.0f);
    float a = bc[c];
    for (int k = 0; k < D_H; ++k)
        a = fmaf(pooled[g * D_H + k] * inv, Wc[k * N_CLS + c], a);
    out[g * N_CLS + c] = a;
}

extern "C" void kernel_launch(void* const* d_in, const int* in_sizes, int n_in,
                              void* d_out, int out_size, void* d_ws, size_t ws_size,
                              hipStream_t stream) {
    const float* x     = (const float*)d_in[0];
    const int*   ei    = (const int*)d_in[1];
    const float* eattr = (const float*)d_in[2];
    const int*   batch = (const int*)d_in[3];
    const float *Wl1 = (const float*)d_in[4],  *bl1 = (const float*)d_in[5];
    const float *Wr1 = (const float*)d_in[6],  *br1 = (const float*)d_in[7];
    const float *We1 = (const float*)d_in[8],  *att1 = (const float*)d_in[9];
    const float *b1  = (const float*)d_in[10];
    const float *Wl2 = (const float*)d_in[11], *bl2 = (const float*)d_in[12];
    const float *Wr2 = (const float*)d_in[13], *br2 = (const float*)d_in[14];
    const float *We2 = (const float*)d_in[15], *att2 = (const float*)d_in[16];
    const float *b2  = (const float*)d_in[17];
    const float *Wc  = (const float*)d_in[18], *bc = (const float*)d_in[19];
    float* out = (float*)d_out;

    const int* src = ei;
    const int* dst = ei + N_EDGES;

    // workspace layout
    float* ws = (float*)d_ws;
    float* xl      = ws;                                // N*64
    float* xr      = xl + (size_t)N_NODES * D_H;        // N*64
    float* h       = xr + (size_t)N_NODES * D_H;        // N*64 (layer outputs)
    float* zsort   = h + (size_t)N_NODES * D_H;         // E2
    int*   csr_src = (int*)(zsort + E2);                // E2
    int*   posbuf  = csr_src + E2;                      // E2
    int*   row_start = posbuf + E2;                     // N+1
    int*   cnt     = row_start + N_NODES + 1;           // N
    int*   cursor  = cnt + N_NODES;                     // N
    float* pooled  = (float*)(cursor + N_NODES);        // 64*64
    float* counts  = pooled + N_GRAPHS * D_H;           // 64
    float* esum    = counts + N_GRAPHS;                 // 1

    const int WPB = 4;  // waves per block at 256 threads
    int edge_wave_blocks = (E2 + WPB - 1) / WPB;
    int node_wave_blocks = (N_NODES + WPB - 1) / WPB;

    hipMemsetAsync(esum, 0, sizeof(float), stream);
    sum_eattr<<<256, 256, 0, stream>>>(eattr, esum, N_EDGES);

    // ---------------- CSR build (once, shared by both layers) ----------------
    init_counts<<<(N_NODES + 255) / 256, 256, 0, stream>>>(cnt);
    hist_dst<<<(N_EDGES + 255) / 256, 256, 0, stream>>>(dst, cnt);
    exscan<<<1, 1024, 0, stream>>>(cnt, row_start);
    hipMemcpyAsync(cursor, row_start, N_NODES * sizeof(int), hipMemcpyDeviceToDevice, stream);
    scatter_edges<<<(N_EDGES + 255) / 256, 256, 0, stream>>>(src, dst, cursor, csr_src, posbuf);
    scatter_self<<<(N_NODES + 255) / 256, 256, 0, stream>>>(cursor, csr_src, posbuf);

    // ---------------- layer 1 ----------------
    linear_dual<<<node_wave_blocks, 256, 0, stream>>>(x, D_IN, Wl1, bl1, Wr1, br1, xl, xr, N_NODES);
    edge_logits<<<edge_wave_blocks, 256, 0, stream>>>(src, dst, eattr, xl, xr, We1, att1, esum, posbuf, zsort);
    node_softmax<<<node_wave_blocks, 256, 0, stream>>>(row_start, zsort);
    node_aggr<<<node_wave_blocks, 256, 0, stream>>>(row_start, csr_src, zsort, xl, b1, h);

    // ---------------- layer 2 ----------------
    linear_dual<<<node_wave_blocks, 256, 0, stream>>>(h, D_H, Wl2, bl2, Wr2, br2, xl, xr, N_NODES);
    edge_logits<<<edge_wave_blocks, 256, 0, stream>>>(src, dst, eattr, xl, xr, We2, att2, esum, posbuf, zsort);
    node_softmax<<<node_wave_blocks, 256, 0, stream>>>(row_start, zsort);
    node_aggr<<<node_wave_blocks, 256, 0, stream>>>(row_start, csr_src, zsort, xl, b2, h);

    // ---------------- pool + classify ----------------
    hipMemsetAsync(pooled, 0, (N_GRAPHS * D_H + N_GRAPHS) * sizeof(float), stream);
    pool<<<(N_NODES + 127) / 128, 64, 0, stream>>>(h, batch, pooled, counts);
    classify<<<1, 640, 0, stream>>>(pooled, counts, Wc, bc, out);
}

// Round 3
// 984.983 us; speedup vs baseline: 1.9947x; 1.6527x over previous
//
#include <hip/hip_runtime.h>
#include <math.h>

#define N_NODES 50000
#define N_EDGES 1600000
#define D_IN 128
#define D_H 64
#define N_CLS 10
#define N_GRAPHS 64
#define NEG_SLOPE 0.2f
#define E2 (N_EDGES + N_NODES)   // edges + self loops

__device__ inline float wave_reduce_sum(float v) {
    for (int off = 32; off; off >>= 1) v += __shfl_xor(v, off);
    return v;
}

// ---- mean of edge_attr (sum; divided by E at use site) ----
__global__ void sum_eattr(const float* __restrict__ ea, float* esum, int E) {
    int i = blockIdx.x * blockDim.x + threadIdx.x;
    float v = 0.f;
    for (; i < E; i += gridDim.x * blockDim.x) v += ea[i];
    v = wave_reduce_sum(v);
    if ((threadIdx.x & 63) == 0) atomicAdd(esum, v);
}

// ============== CSR build (graph shared by both layers) ==============
__global__ void init_counts(int* cnt) {
    int i = blockIdx.x * blockDim.x + threadIdx.x;
    if (i < N_NODES) cnt[i] = 1;   // self loop
}
__global__ void hist_dst(const int* __restrict__ dst, int* cnt) {
    int e = blockIdx.x * blockDim.x + threadIdx.x;
    if (e < N_EDGES) atomicAdd(&cnt[dst[e]], 1);
}
// exclusive scan of cnt[0..N) -> row_start[0..N], single block of 1024
__global__ void exscan(const int* __restrict__ cnt, int* __restrict__ row_start) {
    __shared__ int sdata[1024];
    __shared__ int soff;
    if (threadIdx.x == 0) soff = 0;
    __syncthreads();
    for (int base = 0; base < N_NODES; base += 1024) {
        int i = base + threadIdx.x;
        int v = (i < N_NODES) ? cnt[i] : 0;
        sdata[threadIdx.x] = v;
        __syncthreads();
        for (int off = 1; off < 1024; off <<= 1) {
            int t = (threadIdx.x >= off) ? sdata[threadIdx.x - off] : 0;
            __syncthreads();
            sdata[threadIdx.x] += t;
            __syncthreads();
        }
        int incl = sdata[threadIdx.x];
        if (i < N_NODES) row_start[i] = soff + incl - v;
        __syncthreads();
        if (threadIdx.x == 1023) soff += incl;
        __syncthreads();
    }
    if (threadIdx.x == 0) row_start[N_NODES] = soff;
}
__global__ void scatter_edges(const int* __restrict__ src, const int* __restrict__ dst,
                              const float* __restrict__ eattr,
                              int* cursor, int* __restrict__ csr_src, float* __restrict__ csr_ea) {
    int e = blockIdx.x * blockDim.x + threadIdx.x;
    if (e >= N_EDGES) return;
    int t = dst[e];
    int p = atomicAdd(&cursor[t], 1);
    csr_src[p] = src[e];
    csr_ea[p] = eattr[e];
}
__global__ void scatter_self(const float* __restrict__ esum,
                             int* cursor, int* __restrict__ csr_src, float* __restrict__ csr_ea) {
    int n = blockIdx.x * blockDim.x + threadIdx.x;
    if (n >= N_NODES) return;
    int p = atomicAdd(&cursor[n], 1);
    csr_src[p] = n;
    csr_ea[p] = esum[0] * (1.0f / N_EDGES);
}

// ---- xl = x@Wl + bl ; xr = x@Wr + br.  One wave per node, lane = out dim ----
__global__ void linear_dual(const float* __restrict__ x, int K,
                            const float* __restrict__ Wl, const float* __restrict__ bl,
                            const float* __restrict__ Wr, const float* __restrict__ br,
                            float* __restrict__ xl, float* __restrict__ xr, int n) {
    int node = blockIdx.x * (blockDim.x >> 6) + (threadIdx.x >> 6);
    int d = threadIdx.x & 63;
    if (node >= n) return;
    const float* xrow = x + (size_t)node * K;
    float al = bl[d], ar = br[d];
    for (int k = 0; k < K; ++k) {
        float xv = xrow[k];
        al = fmaf(xv, Wl[k * D_H + d], al);
        ar = fmaf(xv, Wr[k * D_H + d], ar);
    }
    xl[(size_t)node * D_H + d] = al;
    xr[(size_t)node * D_H + d] = ar;
}

// ---- fused GATv2 layer: logits + online softmax + aggregation + bias + ELU ----
// One wave per node; lane = feature dim. xl[src] gathered once per edge.
__global__ void gat_fused(const int* __restrict__ row_start, const int* __restrict__ csr_src,
                          const float* __restrict__ csr_ea,
                          const float* __restrict__ xl, const float* __restrict__ xr,
                          const float* __restrict__ We, const float* __restrict__ att,
                          const float* __restrict__ b, float* __restrict__ out) {
    int node = blockIdx.x * (blockDim.x >> 6) + (threadIdx.x >> 6);
    int d = threadIdx.x & 63;
    if (node >= N_NODES) return;
    float we_d = We[d], att_d = att[d];
    float xr_d = xr[node * D_H + d];
    int j0 = row_start[node], j1 = row_start[node + 1];

    float m = -INFINITY, S = 0.f, acc = 0.f;
    int j = j0;
    // 4-wide: 4 independent 256B gathers in flight, 4 interleaved butterflies
    for (; j + 3 < j1; j += 4) {
        int s0 = csr_src[j], s1 = csr_src[j + 1], s2 = csr_src[j + 2], s3 = csr_src[j + 3];
        float ea0 = csr_ea[j], ea1 = csr_ea[j + 1], ea2 = csr_ea[j + 2], ea3 = csr_ea[j + 3];
        float r0 = xl[s0 * D_H + d];
        float r1 = xl[s1 * D_H + d];
        float r2 = xl[s2 * D_H + d];
        float r3 = xl[s3 * D_H + d];
        float v0 = fmaf(ea0, we_d, r0 + xr_d);
        float v1 = fmaf(ea1, we_d, r1 + xr_d);
        float v2 = fmaf(ea2, we_d, r2 + xr_d);
        float v3 = fmaf(ea3, we_d, r3 + xr_d);
        v0 = v0 > 0.f ? v0 : NEG_SLOPE * v0;
        v1 = v1 > 0.f ? v1 : NEG_SLOPE * v1;
        v2 = v2 > 0.f ? v2 : NEG_SLOPE * v2;
        v3 = v3 > 0.f ? v3 : NEG_SLOPE * v3;
        float t0 = v0 * att_d, t1 = v1 * att_d, t2 = v2 * att_d, t3 = v3 * att_d;
        #pragma unroll
        for (int off = 32; off; off >>= 1) {
            t0 += __shfl_xor(t0, off);
            t1 += __shfl_xor(t1, off);
            t2 += __shfl_xor(t2, off);
            t3 += __shfl_xor(t3, off);
        }
        float pm = fmaxf(fmaxf(t0, t1), fmaxf(t2, t3));
        float m2 = fmaxf(m, pm);
        float sc = expf(m - m2);
        float e0 = expf(t0 - m2), e1 = expf(t1 - m2);
        float e2 = expf(t2 - m2), e3 = expf(t3 - m2);
        S = fmaf(S, sc, e0 + e1 + e2 + e3);
        acc = acc * sc;
        acc = fmaf(e0, r0, acc);
        acc = fmaf(e1, r1, acc);
        acc = fmaf(e2, r2, acc);
        acc = fmaf(e3, r3, acc);
        m = m2;
    }
    for (; j < j1; ++j) {
        int s0 = csr_src[j];
        float ea0 = csr_ea[j];
        float r0 = xl[s0 * D_H + d];
        float v0 = fmaf(ea0, we_d, r0 + xr_d);
        v0 = v0 > 0.f ? v0 : NEG_SLOPE * v0;
        float t0 = v0 * att_d;
        #pragma unroll
        for (int off = 32; off; off >>= 1) t0 += __shfl_xor(t0, off);
        float m2 = fmaxf(m, t0);
        float sc = expf(m - m2);
        float e0 = expf(t0 - m2);
        S = fmaf(S, sc, e0);
        acc = fmaf(e0, r0, acc * sc);
        m = m2;
    }
    float h = acc / (S + 1e-16f) + b[d];
    out[node * D_H + d] = h > 0.f ? h : expm1f(h);
}

// ---- global mean pool (batch is sorted): register accumulate, flush on change ----
__global__ void pool(const float* __restrict__ h, const int* __restrict__ batch,
                     float* __restrict__ pooled, float* __restrict__ counts) {
    const int CHUNK = 128;
    int base = blockIdx.x * CHUNK;
    int d = threadIdx.x;  // blockDim = 64
    float accv = 0.f; int cur_g = -1; int cnt = 0;
    for (int i = 0; i < CHUNK; ++i) {
        int n = base + i;
        if (n >= N_NODES) break;
        int g = batch[n];
        if (g != cur_g) {
            if (cur_g >= 0) {
                atomicAdd(&pooled[cur_g * D_H + d], accv);
                if (d == 0) atomicAdd(&counts[cur_g], (float)cnt);
            }
            cur_g = g; accv = 0.f; cnt = 0;
        }
        accv += h[(size_t)n * D_H + d];
        cnt++;
    }
    if (cur_g >= 0) {
        atomicAdd(&pooled[cur_g * D_H + d], accv);
        if (d == 0) atomicAdd(&counts[cur_g], (float)cnt);
    }
}

__global__ void classify(const float* __restrict__ pooled, const float* __restrict__ counts,
                         const float* __restrict__ Wc, const float* __restrict__ bc,
                         float* __restrict__ out) {
    int tid = threadIdx.x;             // 640 threads
    int g = tid / N_CLS, c = tid % N_CLS;
    if (g >= N_GRAPHS) return;
    float inv = 1.0f / fmaxf(counts[g], 1.0f);
    float a = bc[c];
    for (int k = 0; k < D_H; ++k)
        a = fmaf(pooled[g * D_H + k] * inv, Wc[k * N_CLS + c], a);
    out[g * N_CLS + c] = a;
}

extern "C" void kernel_launch(void* const* d_in, const int* in_sizes, int n_in,
                              void* d_out, int out_size, void* d_ws, size_t ws_size,
                              hipStream_t stream) {
    const float* x     = (const float*)d_in[0];
    const int*   ei    = (const int*)d_in[1];
    const float* eattr = (const float*)d_in[2];
    const int*   batch = (const int*)d_in[3];
    const float *Wl1 = (const float*)d_in[4],  *bl1 = (const float*)d_in[5];
    const float *Wr1 = (const float*)d_in[6],  *br1 = (const float*)d_in[7];
    const float *We1 = (const float*)d_in[8],  *att1 = (const float*)d_in[9];
    const float *b1  = (const float*)d_in[10];
    const float *Wl2 = (const float*)d_in[11], *bl2 = (const float*)d_in[12];
    const float *Wr2 = (const float*)d_in[13], *br2 = (const float*)d_in[14];
    const float *We2 = (const float*)d_in[15], *att2 = (const float*)d_in[16];
    const float *b2  = (const float*)d_in[17];
    const float *Wc  = (const float*)d_in[18], *bc = (const float*)d_in[19];
    float* out = (float*)d_out;

    const int* src = ei;
    const int* dst = ei + N_EDGES;

    // workspace layout
    float* ws = (float*)d_ws;
    float* xl      = ws;                                // N*64
    float* xr      = xl + (size_t)N_NODES * D_H;        // N*64
    float* h       = xr + (size_t)N_NODES * D_H;        // N*64 (layer outputs)
    int*   csr_src = (int*)(h + (size_t)N_NODES * D_H); // E2
    float* csr_ea  = (float*)(csr_src + E2);            // E2
    int*   row_start = (int*)(csr_ea + E2);             // N+1
    int*   cnt     = row_start + N_NODES + 1;           // N
    int*   cursor  = cnt + N_NODES;                     // N
    float* pooled  = (float*)(cursor + N_NODES);        // 64*64
    float* counts  = pooled + N_GRAPHS * D_H;           // 64
    float* esum    = counts + N_GRAPHS;                 // 1

    const int WPB = 4;  // waves per block at 256 threads
    int node_wave_blocks = (N_NODES + WPB - 1) / WPB;

    hipMemsetAsync(esum, 0, sizeof(float), stream);
    sum_eattr<<<256, 256, 0, stream>>>(eattr, esum, N_EDGES);

    // ---------------- CSR build (once, shared by both layers) ----------------
    init_counts<<<(N_NODES + 255) / 256, 256, 0, stream>>>(cnt);
    hist_dst<<<(N_EDGES + 255) / 256, 256, 0, stream>>>(dst, cnt);
    exscan<<<1, 1024, 0, stream>>>(cnt, row_start);
    hipMemcpyAsync(cursor, row_start, N_NODES * sizeof(int), hipMemcpyDeviceToDevice, stream);
    scatter_edges<<<(N_EDGES + 255) / 256, 256, 0, stream>>>(src, dst, eattr, cursor, csr_src, csr_ea);
    scatter_self<<<(N_NODES + 255) / 256, 256, 0, stream>>>(esum, cursor, csr_src, csr_ea);

    // ---------------- layer 1 ----------------
    linear_dual<<<node_wave_blocks, 256, 0, stream>>>(x, D_IN, Wl1, bl1, Wr1, br1, xl, xr, N_NODES);
    gat_fused<<<node_wave_blocks, 256, 0, stream>>>(row_start, csr_src, csr_ea, xl, xr, We1, att1, b1, h);

    // ---------------- layer 2 ----------------
    linear_dual<<<node_wave_blocks, 256, 0, stream>>>(h, D_H, Wl2, bl2, Wr2, br2, xl, xr, N_NODES);
    gat_fused<<<node_wave_blocks, 256, 0, stream>>>(row_start, csr_src, csr_ea, xl, xr, We2, att2, b2, h);

    // ---------------- pool + classify ----------------
    hipMemsetAsync(pooled, 0, (N_GRAPHS * D_H + N_GRAPHS) * sizeof(float), stream);
    pool<<<(N_NODES + 127) / 128, 64, 0, stream>>>(h, batch, pooled, counts);
    classify<<<1, 640, 0, stream>>>(pooled, counts, Wc, bc, out);
}

// Round 4
// 807.940 us; speedup vs baseline: 2.4318x; 1.2191x over previous
//
#include <hip/hip_runtime.h>
#include <math.h>

#define N_NODES 50000
#define N_EDGES 1600000
#define D_IN 128
#define D_H 64
#define N_CLS 10
#define N_GRAPHS 64
#define NEG_SLOPE 0.2f
#define E2 (N_EDGES + N_NODES)   // edges + self loops

__device__ inline float wave_reduce_sum(float v) {
    for (int off = 32; off; off >>= 1) v += __shfl_xor(v, off);
    return v;
}

// ---- mean of edge_attr (sum; divided by E at use site) ----
__global__ void sum_eattr(const float* __restrict__ ea, float* esum, int E) {
    int i = blockIdx.x * blockDim.x + threadIdx.x;
    float v = 0.f;
    for (; i < E; i += gridDim.x * blockDim.x) v += ea[i];
    v = wave_reduce_sum(v);
    if ((threadIdx.x & 63) == 0) atomicAdd(esum, v);
}

// ============== CSR build (graph shared by both layers) ==============
__global__ void init_counts(int* cnt) {
    int i = blockIdx.x * blockDim.x + threadIdx.x;
    if (i < N_NODES) cnt[i] = 1;   // self loop
}
__global__ void hist_dst(const int* __restrict__ dst, int* cnt) {
    int e = blockIdx.x * blockDim.x + threadIdx.x;
    if (e < N_EDGES) atomicAdd(&cnt[dst[e]], 1);
}
// exclusive scan of cnt[0..N) -> row_start[0..N], single block of 1024
__global__ void exscan(const int* __restrict__ cnt, int* __restrict__ row_start) {
    __shared__ int sdata[1024];
    __shared__ int soff;
    if (threadIdx.x == 0) soff = 0;
    __syncthreads();
    for (int base = 0; base < N_NODES; base += 1024) {
        int i = base + threadIdx.x;
        int v = (i < N_NODES) ? cnt[i] : 0;
        sdata[threadIdx.x] = v;
        __syncthreads();
        for (int off = 1; off < 1024; off <<= 1) {
            int t = (threadIdx.x >= off) ? sdata[threadIdx.x - off] : 0;
            __syncthreads();
            sdata[threadIdx.x] += t;
            __syncthreads();
        }
        int incl = sdata[threadIdx.x];
        if (i < N_NODES) row_start[i] = soff + incl - v;
        __syncthreads();
        if (threadIdx.x == 1023) soff += incl;
        __syncthreads();
    }
    if (threadIdx.x == 0) row_start[N_NODES] = soff;
}
// packed CSR entry: .x = src node, .y = edge_attr bits (one 8B store per edge)
__global__ void scatter_edges(const int* __restrict__ src, const int* __restrict__ dst,
                              const float* __restrict__ eattr,
                              int* cursor, int2* __restrict__ csr_pack) {
    int e = blockIdx.x * blockDim.x + threadIdx.x;
    if (e >= N_EDGES) return;
    int t = dst[e];
    int p = atomicAdd(&cursor[t], 1);
    csr_pack[p] = make_int2(src[e], __float_as_int(eattr[e]));
}
__global__ void scatter_self(const float* __restrict__ esum,
                             int* cursor, int2* __restrict__ csr_pack) {
    int n = blockIdx.x * blockDim.x + threadIdx.x;
    if (n >= N_NODES) return;
    int p = atomicAdd(&cursor[n], 1);
    csr_pack[p] = make_int2(n, __float_as_int(esum[0] * (1.0f / N_EDGES)));
}

// ---- xl = x@Wl + bl ; xr = x@Wr + br ----
// 8 nodes per wave, lane = out dim, compile-time K, float4 x loads.
template<int K>
__global__ void linear_dual_k(const float* __restrict__ x,
                              const float* __restrict__ Wl, const float* __restrict__ bl,
                              const float* __restrict__ Wr, const float* __restrict__ br,
                              float* __restrict__ xl, float* __restrict__ xr) {
    const int NPW = 8;
    int wid = blockIdx.x * (blockDim.x >> 6) + (threadIdx.x >> 6);
    int d = threadIdx.x & 63;
    int n0 = wid * NPW;
    if (n0 >= N_NODES) return;
    float blv = bl[d], brv = br[d];
    float al[NPW], ar[NPW];
    #pragma unroll
    for (int i = 0; i < NPW; ++i) { al[i] = blv; ar[i] = brv; }
    const float4* xb = (const float4*)(x + (size_t)n0 * K);
    #pragma unroll 2
    for (int k4 = 0; k4 < K / 4; ++k4) {
        float4 xv[NPW];
        #pragma unroll
        for (int i = 0; i < NPW; ++i) xv[i] = xb[i * (K / 4) + k4];
        int kb = k4 * 4;
        float wl[4], wr[4];
        #pragma unroll
        for (int q = 0; q < 4; ++q) {
            wl[q] = Wl[(kb + q) * D_H + d];
            wr[q] = Wr[(kb + q) * D_H + d];
        }
        #pragma unroll
        for (int i = 0; i < NPW; ++i) {
            al[i] = fmaf(xv[i].x, wl[0], al[i]);
            al[i] = fmaf(xv[i].y, wl[1], al[i]);
            al[i] = fmaf(xv[i].z, wl[2], al[i]);
            al[i] = fmaf(xv[i].w, wl[3], al[i]);
            ar[i] = fmaf(xv[i].x, wr[0], ar[i]);
            ar[i] = fmaf(xv[i].y, wr[1], ar[i]);
            ar[i] = fmaf(xv[i].z, wr[2], ar[i]);
            ar[i] = fmaf(xv[i].w, wr[3], ar[i]);
        }
    }
    #pragma unroll
    for (int i = 0; i < NPW; ++i) {
        xl[(size_t)(n0 + i) * D_H + d] = al[i];
        xr[(size_t)(n0 + i) * D_H + d] = ar[i];
    }
}

// ---- fused GATv2 layer: logits + online softmax + aggregation + bias + ELU ----
__global__ void gat_fused(const int* __restrict__ row_start, const int2* __restrict__ csr_pack,
                          const float* __restrict__ xl, const float* __restrict__ xr,
                          const float* __restrict__ We, const float* __restrict__ att,
                          const float* __restrict__ b, float* __restrict__ out) {
    int node = blockIdx.x * (blockDim.x >> 6) + (threadIdx.x >> 6);
    int d = threadIdx.x & 63;
    if (node >= N_NODES) return;
    float we_d = We[d], att_d = att[d];
    float xr_d = xr[node * D_H + d];
    int j0 = row_start[node], j1 = row_start[node + 1];

    float m = -INFINITY, S = 0.f, acc = 0.f;
    int j = j0;
    for (; j + 3 < j1; j += 4) {
        int2 p0 = csr_pack[j], p1 = csr_pack[j + 1], p2 = csr_pack[j + 2], p3 = csr_pack[j + 3];
        float r0 = xl[p0.x * D_H + d];
        float r1 = xl[p1.x * D_H + d];
        float r2 = xl[p2.x * D_H + d];
        float r3 = xl[p3.x * D_H + d];
        float v0 = fmaf(__int_as_float(p0.y), we_d, r0 + xr_d);
        float v1 = fmaf(__int_as_float(p1.y), we_d, r1 + xr_d);
        float v2 = fmaf(__int_as_float(p2.y), we_d, r2 + xr_d);
        float v3 = fmaf(__int_as_float(p3.y), we_d, r3 + xr_d);
        v0 = v0 > 0.f ? v0 : NEG_SLOPE * v0;
        v1 = v1 > 0.f ? v1 : NEG_SLOPE * v1;
        v2 = v2 > 0.f ? v2 : NEG_SLOPE * v2;
        v3 = v3 > 0.f ? v3 : NEG_SLOPE * v3;
        float t0 = v0 * att_d, t1 = v1 * att_d, t2 = v2 * att_d, t3 = v3 * att_d;
        #pragma unroll
        for (int off = 32; off; off >>= 1) {
            t0 += __shfl_xor(t0, off);
            t1 += __shfl_xor(t1, off);
            t2 += __shfl_xor(t2, off);
            t3 += __shfl_xor(t3, off);
        }
        float pm = fmaxf(fmaxf(t0, t1), fmaxf(t2, t3));
        float m2 = fmaxf(m, pm);
        float sc = expf(m - m2);
        float e0 = expf(t0 - m2), e1 = expf(t1 - m2);
        float e2 = expf(t2 - m2), e3 = expf(t3 - m2);
        S = fmaf(S, sc, e0 + e1 + e2 + e3);
        acc = acc * sc;
        acc = fmaf(e0, r0, acc);
        acc = fmaf(e1, r1, acc);
        acc = fmaf(e2, r2, acc);
        acc = fmaf(e3, r3, acc);
        m = m2;
    }
    for (; j < j1; ++j) {
        int2 p0 = csr_pack[j];
        float r0 = xl[p0.x * D_H + d];
        float v0 = fmaf(__int_as_float(p0.y), we_d, r0 + xr_d);
        v0 = v0 > 0.f ? v0 : NEG_SLOPE * v0;
        float t0 = v0 * att_d;
        #pragma unroll
        for (int off = 32; off; off >>= 1) t0 += __shfl_xor(t0, off);
        float m2 = fmaxf(m, t0);
        float sc = expf(m - m2);
        float e0 = expf(t0 - m2);
        S = fmaf(S, sc, e0);
        acc = fmaf(e0, r0, acc * sc);
        m = m2;
    }
    float h = acc / (S + 1e-16f) + b[d];
    out[node * D_H + d] = h > 0.f ? h : expm1f(h);
}

// ---- global mean pool (batch is sorted): register accumulate, flush on change ----
__global__ void pool(const float* __restrict__ h, const int* __restrict__ batch,
                     float* __restrict__ pooled, float* __restrict__ counts) {
    const int CHUNK = 128;
    int base = blockIdx.x * CHUNK;
    int d = threadIdx.x;  // blockDim = 64
    float accv = 0.f; int cur_g = -1; int cnt = 0;
    for (int i = 0; i < CHUNK; ++i) {
        int n = base + i;
        if (n >= N_NODES) break;
        int g = batch[n];
        if (g != cur_g) {
            if (cur_g >= 0) {
                atomicAdd(&pooled[cur_g * D_H + d], accv);
                if (d == 0) atomicAdd(&counts[cur_g], (float)cnt);
            }
            cur_g = g; accv = 0.f; cnt = 0;
        }
        accv += h[(size_t)n * D_H + d];
        cnt++;
    }
    if (cur_g >= 0) {
        atomicAdd(&pooled[cur_g * D_H + d], accv);
        if (d == 0) atomicAdd(&counts[cur_g], (float)cnt);
    }
}

__global__ void classify(const float* __restrict__ pooled, const float* __restrict__ counts,
                         const float* __restrict__ Wc, const float* __restrict__ bc,
                         float* __restrict__ out) {
    int tid = threadIdx.x;             // 640 threads
    int g = tid / N_CLS, c = tid % N_CLS;
    if (g >= N_GRAPHS) return;
    float inv = 1.0f / fmaxf(counts[g], 1.0f);
    float a = bc[c];
    for (int k = 0; k < D_H; ++k)
        a = fmaf(pooled[g * D_H + k] * inv, Wc[k * N_CLS + c], a);
    out[g * N_CLS + c] = a;
}

extern "C" void kernel_launch(void* const* d_in, const int* in_sizes, int n_in,
                              void* d_out, int out_size, void* d_ws, size_t ws_size,
                              hipStream_t stream) {
    const float* x     = (const float*)d_in[0];
    const int*   ei    = (const int*)d_in[1];
    const float* eattr = (const float*)d_in[2];
    const int*   batch = (const int*)d_in[3];
    const float *Wl1 = (const float*)d_in[4],  *bl1 = (const float*)d_in[5];
    const float *Wr1 = (const float*)d_in[6],  *br1 = (const float*)d_in[7];
    const float *We1 = (const float*)d_in[8],  *att1 = (const float*)d_in[9];
    const float *b1  = (const float*)d_in[10];
    const float *Wl2 = (const float*)d_in[11], *bl2 = (const float*)d_in[12];
    const float *Wr2 = (const float*)d_in[13], *br2 = (const float*)d_in[14];
    const float *We2 = (const float*)d_in[15], *att2 = (const float*)d_in[16];
    const float *b2  = (const float*)d_in[17];
    const float *Wc  = (const float*)d_in[18], *bc = (const float*)d_in[19];
    float* out = (float*)d_out;

    const int* src = ei;
    const int* dst = ei + N_EDGES;

    // workspace layout
    float* ws = (float*)d_ws;
    float* xl      = ws;                                // N*64
    float* xr      = xl + (size_t)N_NODES * D_H;        // N*64
    float* h       = xr + (size_t)N_NODES * D_H;        // N*64 (layer outputs)
    int2*  csr_pack = (int2*)(h + (size_t)N_NODES * D_H); // E2 (8B each)
    int*   row_start = (int*)(csr_pack + E2);           // N+1
    int*   cnt     = row_start + N_NODES + 1;           // N
    int*   cursor  = cnt + N_NODES;                     // N
    float* pooled  = (float*)(cursor + N_NODES);        // 64*64
    float* counts  = pooled + N_GRAPHS * D_H;           // 64
    float* esum    = counts + N_GRAPHS;                 // 1

    const int WPB = 4;  // waves per block at 256 threads
    int node_wave_blocks = (N_NODES + WPB - 1) / WPB;
    int lin_blocks = (N_NODES / 8 + WPB - 1) / WPB;

    hipMemsetAsync(esum, 0, sizeof(float), stream);
    sum_eattr<<<256, 256, 0, stream>>>(eattr, esum, N_EDGES);

    // ---------------- CSR build (once, shared by both layers) ----------------
    init_counts<<<(N_NODES + 255) / 256, 256, 0, stream>>>(cnt);
    hist_dst<<<(N_EDGES + 255) / 256, 256, 0, stream>>>(dst, cnt);
    exscan<<<1, 1024, 0, stream>>>(cnt, row_start);
    hipMemcpyAsync(cursor, row_start, N_NODES * sizeof(int), hipMemcpyDeviceToDevice, stream);
    scatter_edges<<<(N_EDGES + 255) / 256, 256, 0, stream>>>(src, dst, eattr, cursor, csr_pack);
    scatter_self<<<(N_NODES + 255) / 256, 256, 0, stream>>>(esum, cursor, csr_pack);

    // ---------------- layer 1 ----------------
    linear_dual_k<D_IN><<<lin_blocks, 256, 0, stream>>>(x, Wl1, bl1, Wr1, br1, xl, xr);
    gat_fused<<<node_wave_blocks, 256, 0, stream>>>(row_start, csr_pack, xl, xr, We1, att1, b1, h);

    // ---------------- layer 2 ----------------
    linear_dual_k<D_H><<<lin_blocks, 256, 0, stream>>>(h, Wl2, bl2, Wr2, br2, xl, xr);
    gat_fused<<<node_wave_blocks, 256, 0, stream>>>(row_start, csr_pack, xl, xr, We2, att2, b2, h);

    // ---------------- pool + classify ----------------
    hipMemsetAsync(pooled, 0, (N_GRAPHS * D_H + N_GRAPHS) * sizeof(float), stream);
    pool<<<(N_NODES + 127) / 128, 64, 0, stream>>>(h, batch, pooled, counts);
    classify<<<1, 640, 0, stream>>>(pooled, counts, Wc, bc, out);
}

// Round 5
// 606.908 us; speedup vs baseline: 3.2373x; 1.3312x over previous
//
#include <hip/hip_runtime.h>
#include <math.h>

#define N_NODES 50000
#define N_EDGES 1600000
#define D_IN 128
#define D_H 64
#define N_CLS 10
#define N_GRAPHS 64
#define NEG_SLOPE 0.2f
#define E2 (N_EDGES + N_NODES)   // edges + self loops
#define SCAN_BS 256
#define NBLK ((N_NODES + SCAN_BS - 1) / SCAN_BS)   // 196 <= 256

__device__ inline float wave_reduce_sum(float v) {
    for (int off = 32; off; off >>= 1) v += __shfl_xor(v, off);
    return v;
}

// ---- mean of edge_attr (sum; divided by E at use site) ----
__global__ void sum_eattr(const float* __restrict__ ea, float* esum, int E) {
    int i = blockIdx.x * blockDim.x + threadIdx.x;
    float v = 0.f;
    for (; i < E; i += gridDim.x * blockDim.x) v += ea[i];
    v = wave_reduce_sum(v);
    if ((threadIdx.x & 63) == 0) atomicAdd(esum, v);
}

// ============== CSR build (graph shared by both layers) ==============
__global__ void init_counts(int* cnt) {
    int i = blockIdx.x * blockDim.x + threadIdx.x;
    if (i < N_NODES) cnt[i] = 1;   // self loop
}
__global__ void hist_dst(const int* __restrict__ dst, int* cnt) {
    int e = blockIdx.x * blockDim.x + threadIdx.x;
    if (e < N_EDGES) atomicAdd(&cnt[dst[e]], 1);
}

// ---- hierarchical exclusive scan: block scan -> partial scan -> add offsets ----
__global__ void scan_block(const int* __restrict__ cnt, int* __restrict__ row_start,
                           int* __restrict__ partial) {
    __shared__ int sd[SCAN_BS];
    int i = blockIdx.x * SCAN_BS + threadIdx.x;
    int v = (i < N_NODES) ? cnt[i] : 0;
    sd[threadIdx.x] = v;
    __syncthreads();
    for (int off = 1; off < SCAN_BS; off <<= 1) {
        int t = (threadIdx.x >= off) ? sd[threadIdx.x - off] : 0;
        __syncthreads();
        sd[threadIdx.x] += t;
        __syncthreads();
    }
    if (i < N_NODES) row_start[i] = sd[threadIdx.x] - v;       // exclusive within block
    if (threadIdx.x == SCAN_BS - 1) partial[blockIdx.x] = sd[threadIdx.x];
}
__global__ void scan_partials(int* partial) {   // one block of 256
    __shared__ int sd[SCAN_BS];
    int v = (threadIdx.x < NBLK) ? partial[threadIdx.x] : 0;
    sd[threadIdx.x] = v;
    __syncthreads();
    for (int off = 1; off < SCAN_BS; off <<= 1) {
        int t = (threadIdx.x >= off) ? sd[threadIdx.x - off] : 0;
        __syncthreads();
        sd[threadIdx.x] += t;
        __syncthreads();
    }
    if (threadIdx.x < NBLK) partial[threadIdx.x] = sd[threadIdx.x] - v;  // exclusive
}
__global__ void add_offsets(int* __restrict__ row_start, const int* __restrict__ partial,
                            int* __restrict__ cursor) {
    int i = blockIdx.x * SCAN_BS + threadIdx.x;
    if (i < N_NODES) {
        int r = row_start[i] + partial[blockIdx.x];
        row_start[i] = r;
        cursor[i] = r;
    }
    if (i == 0) row_start[N_NODES] = E2;   // total is static
}

// packed CSR entry: .x = src node, .y = edge_attr bits
__global__ void scatter_edges(const int* __restrict__ src, const int* __restrict__ dst,
                              const float* __restrict__ eattr,
                              int* cursor, int2* __restrict__ csr_pack) {
    int e = blockIdx.x * blockDim.x + threadIdx.x;
    if (e >= N_EDGES) return;
    int t = dst[e];
    int p = atomicAdd(&cursor[t], 1);
    csr_pack[p] = make_int2(src[e], __float_as_int(eattr[e]));
}
__global__ void scatter_self(const float* __restrict__ esum,
                             int* cursor, int2* __restrict__ csr_pack) {
    int n = blockIdx.x * blockDim.x + threadIdx.x;
    if (n >= N_NODES) return;
    int p = atomicAdd(&cursor[n], 1);
    csr_pack[p] = make_int2(n, __float_as_int(esum[0] * (1.0f / N_EDGES)));
}

// ---- xl = x@Wl + bl ; xr = x@Wr + br ----
// 8 nodes per wave, lane = out dim, compile-time K, float4 x loads.
template<int K>
__global__ void linear_dual_k(const float* __restrict__ x,
                              const float* __restrict__ Wl, const float* __restrict__ bl,
                              const float* __restrict__ Wr, const float* __restrict__ br,
                              float* __restrict__ xl, float* __restrict__ xr) {
    const int NPW = 8;
    int wid = blockIdx.x * (blockDim.x >> 6) + (threadIdx.x >> 6);
    int d = threadIdx.x & 63;
    int n0 = wid * NPW;
    if (n0 >= N_NODES) return;
    float blv = bl[d], brv = br[d];
    float al[NPW], ar[NPW];
    #pragma unroll
    for (int i = 0; i < NPW; ++i) { al[i] = blv; ar[i] = brv; }
    const float4* xb = (const float4*)(x + (size_t)n0 * K);
    #pragma unroll 2
    for (int k4 = 0; k4 < K / 4; ++k4) {
        float4 xv[NPW];
        #pragma unroll
        for (int i = 0; i < NPW; ++i) xv[i] = xb[i * (K / 4) + k4];
        int kb = k4 * 4;
        float wl[4], wr[4];
        #pragma unroll
        for (int q = 0; q < 4; ++q) {
            wl[q] = Wl[(kb + q) * D_H + d];
            wr[q] = Wr[(kb + q) * D_H + d];
        }
        #pragma unroll
        for (int i = 0; i < NPW; ++i) {
            al[i] = fmaf(xv[i].x, wl[0], al[i]);
            al[i] = fmaf(xv[i].y, wl[1], al[i]);
            al[i] = fmaf(xv[i].z, wl[2], al[i]);
            al[i] = fmaf(xv[i].w, wl[3], al[i]);
            ar[i] = fmaf(xv[i].x, wr[0], ar[i]);
            ar[i] = fmaf(xv[i].y, wr[1], ar[i]);
            ar[i] = fmaf(xv[i].z, wr[2], ar[i]);
            ar[i] = fmaf(xv[i].w, wr[3], ar[i]);
        }
    }
    #pragma unroll
    for (int i = 0; i < NPW; ++i) {
        xl[(size_t)(n0 + i) * D_H + d] = al[i];
        xr[(size_t)(n0 + i) * D_H + d] = ar[i];
    }
}

// ---- fused GATv2 layer, 16-lane-group layout ----
// Wave per node. lane = g*16+s; lane holds features [4s,4s+4). 4 groups process
// 8 edges/iter (2 each). Online softmax per group, merged at the end.
__global__ void gat_fused(const int* __restrict__ row_start, const int2* __restrict__ csr_pack,
                          const float* __restrict__ xl, const float* __restrict__ xr,
                          const float* __restrict__ We, const float* __restrict__ att,
                          const float* __restrict__ b, float* __restrict__ out) {
    int node = blockIdx.x * (blockDim.x >> 6) + (threadIdx.x >> 6);
    if (node >= N_NODES) return;
    int lane = threadIdx.x & 63;
    int g = lane >> 4;          // group 0..3
    int s = lane & 15;          // sublane 0..15
    int fb = s * 4;             // feature base
    float4 we4  = *(const float4*)(We + fb);
    float4 att4 = *(const float4*)(att + fb);
    float4 xr4  = *(const float4*)(xr + (size_t)node * D_H + fb);
    int j0 = row_start[node], j1 = row_start[node + 1];

    float m = -1e30f, S = 0.f;
    float4 acc = make_float4(0.f, 0.f, 0.f, 0.f);

    for (int base = j0; base < j1; base += 8) {
        int ia = base + 2 * g;
        int ib = ia + 1;
        bool va = ia < j1, vb = ib < j1;
        int ca = va ? ia : j0;           // clamp to a valid slot
        int cb = vb ? ib : j0;
        int2 pa = csr_pack[ca], pb = csr_pack[cb];
        float4 ra = *(const float4*)(xl + (size_t)pa.x * D_H + fb);
        float4 rb = *(const float4*)(xl + (size_t)pb.x * D_H + fb);
        float eaa = __int_as_float(pa.y), eab = __int_as_float(pb.y);

        float4 vA, vB;
        vA.x = fmaf(eaa, we4.x, ra.x + xr4.x);
        vA.y = fmaf(eaa, we4.y, ra.y + xr4.y);
        vA.z = fmaf(eaa, we4.z, ra.z + xr4.z);
        vA.w = fmaf(eaa, we4.w, ra.w + xr4.w);
        vB.x = fmaf(eab, we4.x, rb.x + xr4.x);
        vB.y = fmaf(eab, we4.y, rb.y + xr4.y);
        vB.z = fmaf(eab, we4.z, rb.z + xr4.z);
        vB.w = fmaf(eab, we4.w, rb.w + xr4.w);
        // leaky = max(x, 0.2x) since slope < 1
        vA.x = fmaxf(vA.x, NEG_SLOPE * vA.x);
        vA.y = fmaxf(vA.y, NEG_SLOPE * vA.y);
        vA.z = fmaxf(vA.z, NEG_SLOPE * vA.z);
        vA.w = fmaxf(vA.w, NEG_SLOPE * vA.w);
        vB.x = fmaxf(vB.x, NEG_SLOPE * vB.x);
        vB.y = fmaxf(vB.y, NEG_SLOPE * vB.y);
        vB.z = fmaxf(vB.z, NEG_SLOPE * vB.z);
        vB.w = fmaxf(vB.w, NEG_SLOPE * vB.w);

        float ta = fmaf(vA.w, att4.w, fmaf(vA.z, att4.z, fmaf(vA.y, att4.y, vA.x * att4.x)));
        float tb = fmaf(vB.w, att4.w, fmaf(vB.z, att4.z, fmaf(vB.y, att4.y, vB.x * att4.x)));
        #pragma unroll
        for (int off = 1; off <= 8; off <<= 1) {   // stays inside the 16-lane group
            ta += __shfl_xor(ta, off);
            tb += __shfl_xor(tb, off);
        }
        ta = va ? ta : -INFINITY;
        tb = vb ? tb : -INFINITY;

        float m2 = fmaxf(m, fmaxf(ta, tb));
        float sc = __expf(m - m2);        // m,m2 finite (init -1e30) -> no NaN
        float ezA = __expf(ta - m2);      // -INF - finite -> 0
        float ezB = __expf(tb - m2);
        S = fmaf(S, sc, ezA + ezB);
        acc.x = fmaf(acc.x, sc, fmaf(ezA, ra.x, ezB * rb.x));
        acc.y = fmaf(acc.y, sc, fmaf(ezA, ra.y, ezB * rb.y));
        acc.z = fmaf(acc.z, sc, fmaf(ezA, ra.z, ezB * rb.z));
        acc.w = fmaf(acc.w, sc, fmaf(ezA, ra.w, ezB * rb.w));
        m = m2;
    }

    // merge the 4 groups' online-softmax states (xor 16, then xor 32)
    #pragma unroll
    for (int off = 16; off <= 32; off <<= 1) {
        float mo = __shfl_xor(m, off);
        float So = __shfl_xor(S, off);
        float aox = __shfl_xor(acc.x, off);
        float aoy = __shfl_xor(acc.y, off);
        float aoz = __shfl_xor(acc.z, off);
        float aow = __shfl_xor(acc.w, off);
        float M2 = fmaxf(m, mo);
        float sa = __expf(m - M2), sb = __expf(mo - M2);
        S = S * sa + So * sb;
        acc.x = acc.x * sa + aox * sb;
        acc.y = acc.y * sa + aoy * sb;
        acc.z = acc.z * sa + aoz * sb;
        acc.w = acc.w * sa + aow * sb;
        m = M2;
    }

    if (g == 0) {
        float4 b4 = *(const float4*)(b + fb);
        float inv = 1.f / (S + 1e-16f);
        float4 h;
        h.x = fmaf(acc.x, inv, b4.x);
        h.y = fmaf(acc.y, inv, b4.y);
        h.z = fmaf(acc.z, inv, b4.z);
        h.w = fmaf(acc.w, inv, b4.w);
        h.x = h.x > 0.f ? h.x : expm1f(h.x);
        h.y = h.y > 0.f ? h.y : expm1f(h.y);
        h.z = h.z > 0.f ? h.z : expm1f(h.z);
        h.w = h.w > 0.f ? h.w : expm1f(h.w);
        *(float4*)(out + (size_t)node * D_H + fb) = h;
    }
}

// ---- global mean pool (batch is sorted): register accumulate, flush on change ----
__global__ void pool(const float* __restrict__ h, const int* __restrict__ batch,
                     float* __restrict__ pooled, float* __restrict__ counts) {
    const int CHUNK = 128;
    int base = blockIdx.x * CHUNK;
    int d = threadIdx.x;  // blockDim = 64
    float accv = 0.f; int cur_g = -1; int cnt = 0;
    for (int i = 0; i < CHUNK; ++i) {
        int n = base + i;
        if (n >= N_NODES) break;
        int g = batch[n];
        if (g != cur_g) {
            if (cur_g >= 0) {
                atomicAdd(&pooled[cur_g * D_H + d], accv);
                if (d == 0) atomicAdd(&counts[cur_g], (float)cnt);
            }
            cur_g = g; accv = 0.f; cnt = 0;
        }
        accv += h[(size_t)n * D_H + d];
        cnt++;
    }
    if (cur_g >= 0) {
        atomicAdd(&pooled[cur_g * D_H + d], accv);
        if (d == 0) atomicAdd(&counts[cur_g], (float)cnt);
    }
}

__global__ void classify(const float* __restrict__ pooled, const float* __restrict__ counts,
                         const float* __restrict__ Wc, const float* __restrict__ bc,
                         float* __restrict__ out) {
    int tid = threadIdx.x;             // 640 threads
    int g = tid / N_CLS, c = tid % N_CLS;
    if (g >= N_GRAPHS) return;
    float inv = 1.0f / fmaxf(counts[g], 1.0f);
    float a = bc[c];
    for (int k = 0; k < D_H; ++k)
        a = fmaf(pooled[g * D_H + k] * inv, Wc[k * N_CLS + c], a);
    out[g * N_CLS + c] = a;
}

extern "C" void kernel_launch(void* const* d_in, const int* in_sizes, int n_in,
                              void* d_out, int out_size, void* d_ws, size_t ws_size,
                              hipStream_t stream) {
    const float* x     = (const float*)d_in[0];
    const int*   ei    = (const int*)d_in[1];
    const float* eattr = (const float*)d_in[2];
    const int*   batch = (const int*)d_in[3];
    const float *Wl1 = (const float*)d_in[4],  *bl1 = (const float*)d_in[5];
    const float *Wr1 = (const float*)d_in[6],  *br1 = (const float*)d_in[7];
    const float *We1 = (const float*)d_in[8],  *att1 = (const float*)d_in[9];
    const float *b1  = (const float*)d_in[10];
    const float *Wl2 = (const float*)d_in[11], *bl2 = (const float*)d_in[12];
    const float *Wr2 = (const float*)d_in[13], *br2 = (const float*)d_in[14];
    const float *We2 = (const float*)d_in[15], *att2 = (const float*)d_in[16];
    const float *b2  = (const float*)d_in[17];
    const float *Wc  = (const float*)d_in[18], *bc = (const float*)d_in[19];
    float* out = (float*)d_out;

    const int* src = ei;
    const int* dst = ei + N_EDGES;

    // workspace layout
    float* ws = (float*)d_ws;
    float* xl      = ws;                                // N*64
    float* xr      = xl + (size_t)N_NODES * D_H;        // N*64
    float* h       = xr + (size_t)N_NODES * D_H;        // N*64 (layer outputs)
    int2*  csr_pack = (int2*)(h + (size_t)N_NODES * D_H); // E2 (8B each)
    int*   row_start = (int*)(csr_pack + E2);           // N+1
    int*   cnt     = row_start + N_NODES + 1;           // N
    int*   cursor  = cnt + N_NODES;                     // N
    int*   partial = cursor + N_NODES;                  // NBLK
    float* pooled  = (float*)(partial + NBLK);          // 64*64
    float* counts  = pooled + N_GRAPHS * D_H;           // 64
    float* esum    = counts + N_GRAPHS;                 // 1

    const int WPB = 4;  // waves per block at 256 threads
    int node_wave_blocks = (N_NODES + WPB - 1) / WPB;
    int lin_blocks = (N_NODES / 8 + WPB - 1) / WPB;

    hipMemsetAsync(esum, 0, sizeof(float), stream);
    sum_eattr<<<256, 256, 0, stream>>>(eattr, esum, N_EDGES);

    // ---------------- CSR build (once, shared by both layers) ----------------
    init_counts<<<(N_NODES + 255) / 256, 256, 0, stream>>>(cnt);
    hist_dst<<<(N_EDGES + 255) / 256, 256, 0, stream>>>(dst, cnt);
    scan_block<<<NBLK, SCAN_BS, 0, stream>>>(cnt, row_start, partial);
    scan_partials<<<1, SCAN_BS, 0, stream>>>(partial);
    add_offsets<<<NBLK, SCAN_BS, 0, stream>>>(row_start, partial, cursor);
    scatter_edges<<<(N_EDGES + 255) / 256, 256, 0, stream>>>(src, dst, eattr, cursor, csr_pack);
    scatter_self<<<(N_NODES + 255) / 256, 256, 0, stream>>>(esum, cursor, csr_pack);

    // ---------------- layer 1 ----------------
    linear_dual_k<D_IN><<<lin_blocks, 256, 0, stream>>>(x, Wl1, bl1, Wr1, br1, xl, xr);
    gat_fused<<<node_wave_blocks, 256, 0, stream>>>(row_start, csr_pack, xl, xr, We1, att1, b1, h);

    // ---------------- layer 2 ----------------
    linear_dual_k<D_H><<<lin_blocks, 256, 0, stream>>>(h, Wl2, bl2, Wr2, br2, xl, xr);
    gat_fused<<<node_wave_blocks, 256, 0, stream>>>(row_start, csr_pack, xl, xr, We2, att2, b2, h);

    // ---------------- pool + classify ----------------
    hipMemsetAsync(pooled, 0, (N_GRAPHS * D_H + N_GRAPHS) * sizeof(float), stream);
    pool<<<(N_NODES + 127) / 128, 64, 0, stream>>>(h, batch, pooled, counts);
    classify<<<1, 640, 0, stream>>>(pooled, counts, Wc, bc, out);
}